// Round 9
// baseline (49.005 us; speedup 1.0000x reference)
//
#include <hip/hip_runtime.h>

#define NDIM 128   // feature dim D
#define NOUT 8     // output dim

typedef float     f32x4 __attribute__((ext_vector_type(4)));
typedef _Float16  f16x8 __attribute__((ext_vector_type(8)));

// Kernel 1 (v4, unchanged): per-node projection via MFMA.
// One wave computes a 16-node x 16-output tile: D = A(16x128) x B(128x16)
// as 4 x mfma_f32_16x16x32_f16, f32 accumulate. No LDS.
//   P[n][0..7]  = h[n].Wu[o]          (src half)
//   P[n][8..15] = h[n].Wv[o] + b[o]   (dst half, bias baked in)
// Layouts (gfx950 16x16x32): A: row=lane&15, k=(lane>>4)*8+j (8 contiguous);
// B: col=lane&15, same k slice; D: col=lane&15, row=(lane>>4)*4+reg.
__global__ __launch_bounds__(256) void node_proj_kernel(
    const float* __restrict__ h, const float* __restrict__ W,
    const float* __restrict__ b, _Float16* __restrict__ P, int n_nodes) {
  const int lane = threadIdx.x & 63;
  const int wv   = threadIdx.x >> 6;           // wave id in block (0..3)
  const int nb   = blockIdx.x * 64 + wv * 16;  // this wave's base node
  const int c    = lane & 15;                  // A-row / B-col / D-col
  const int kg   = lane >> 4;                  // k-group (0..3)

  // B fragments: W'[col=c][k], combined row c: c<8 -> Wu[c], c>=8 -> Wv[c-8].
  // W is [8][256] with Wu = cols 0..127, Wv = cols 128..255.
  const float* __restrict__ wp =
      W + (c & 7) * (2 * NDIM) + (c >> 3) * NDIM + kg * 8;
  f16x8 bf[4];
#pragma unroll
  for (int s = 0; s < 4; ++s) {
    const f32x4 w0 = *reinterpret_cast<const f32x4*>(wp + s * 32);
    const f32x4 w1 = *reinterpret_cast<const f32x4*>(wp + s * 32 + 4);
    f16x8 t;
    t[0] = (_Float16)w0.x; t[1] = (_Float16)w0.y;
    t[2] = (_Float16)w0.z; t[3] = (_Float16)w0.w;
    t[4] = (_Float16)w1.x; t[5] = (_Float16)w1.y;
    t[6] = (_Float16)w1.z; t[7] = (_Float16)w1.w;
    bf[s] = t;
  }

  // A fragments: h[node=nb+c][k], k = s*32 + kg*8 .. +8 (f32 -> f16).
  const int node = nb + c;
  const bool valid = node < n_nodes;
  const float* __restrict__ hp = h + (size_t)node * NDIM + kg * 8;

  f32x4 acc = {0.f, 0.f, 0.f, 0.f};
#pragma unroll
  for (int s = 0; s < 4; ++s) {
    f16x8 af = {};
    if (valid) {
      const f32x4 a0 = *reinterpret_cast<const f32x4*>(hp + s * 32);
      const f32x4 a1 = *reinterpret_cast<const f32x4*>(hp + s * 32 + 4);
      af[0] = (_Float16)a0.x; af[1] = (_Float16)a0.y;
      af[2] = (_Float16)a0.z; af[3] = (_Float16)a0.w;
      af[4] = (_Float16)a1.x; af[5] = (_Float16)a1.y;
      af[6] = (_Float16)a1.z; af[7] = (_Float16)a1.w;
    }
    acc = __builtin_amdgcn_mfma_f32_16x16x32_f16(af, bf[s], acc, 0, 0, 0);
  }

  // Epilogue: lane writes D rows kg*4..kg*4+3, col c. Bias on dst half.
  const float bias = (c >= 8) ? b[c - 8] : 0.f;
#pragma unroll
  for (int i = 0; i < 4; ++i) {
    const int nrow = nb + kg * 4 + i;
    if (nrow < n_nodes)
      P[(size_t)nrow * 16 + c] = (_Float16)(acc[i] + bias);
  }
}

// Kernel 2 (v4): per-edge gather + add, 4 edges/thread at +256 stride.
// Index loads and output stores stay lane-coalesced; all 8 gathers are
// issued back-to-back before any use -> 2x memory-level parallelism to
// hide the L2/L3 random-gather latency. P (fp16, 3.2MB) fits per-XCD L2;
// streaming traffic (indices, out) is nontemporal to protect residency.
__global__ __launch_bounds__(256) void edge_score_kernel(
    const int* __restrict__ src, const int* __restrict__ dst,
    const _Float16* __restrict__ P, float* __restrict__ out, int n_edges) {
  const int t = threadIdx.x;
  const int base = blockIdx.x * 1024 + t;

  const f16x8* __restrict__ Pp = reinterpret_cast<const f16x8*>(P);
  f32x4* __restrict__ op = reinterpret_cast<f32x4*>(out);

  int e[4], si[4], di[4];
  bool v[4];
#pragma unroll
  for (int k = 0; k < 4; ++k) {
    e[k] = base + k * 256;
    v[k] = e[k] < n_edges;
    si[k] = v[k] ? __builtin_nontemporal_load(src + e[k]) : 0;
    di[k] = v[k] ? __builtin_nontemporal_load(dst + e[k]) : 0;
  }

  f16x8 sv[4], dv[4];
#pragma unroll
  for (int k = 0; k < 4; ++k) {
    sv[k] = Pp[(size_t)si[k] * 2 + 0];   // src half of node si[k]
    dv[k] = Pp[(size_t)di[k] * 2 + 1];   // dst half of node di[k]
  }

#pragma unroll
  for (int k = 0; k < 4; ++k) {
    if (v[k]) {
      f32x4 r0, r1;
      r0.x = (float)sv[k][0] + (float)dv[k][0];
      r0.y = (float)sv[k][1] + (float)dv[k][1];
      r0.z = (float)sv[k][2] + (float)dv[k][2];
      r0.w = (float)sv[k][3] + (float)dv[k][3];
      r1.x = (float)sv[k][4] + (float)dv[k][4];
      r1.y = (float)sv[k][5] + (float)dv[k][5];
      r1.z = (float)sv[k][6] + (float)dv[k][6];
      r1.w = (float)sv[k][7] + (float)dv[k][7];
      __builtin_nontemporal_store(r0, op + (size_t)e[k] * 2 + 0);
      __builtin_nontemporal_store(r1, op + (size_t)e[k] * 2 + 1);
    }
  }
}

// Fallback (only if workspace is too small): direct per-edge computation.
__global__ __launch_bounds__(256) void edge_direct_kernel(
    const float* __restrict__ h, const int* __restrict__ src,
    const int* __restrict__ dst, const float* __restrict__ W,
    const float* __restrict__ b, float* __restrict__ out, int n_edges) {
  const int e = blockIdx.x * 256 + threadIdx.x;
  if (e >= n_edges) return;
  const int s = src[e];
  const int d = dst[e];
  const float4* __restrict__ hs = reinterpret_cast<const float4*>(h + (size_t)s * NDIM);
  const float4* __restrict__ hd = reinterpret_cast<const float4*>(h + (size_t)d * NDIM);
  const float4* __restrict__ W4 = reinterpret_cast<const float4*>(W);

  float acc[NOUT];
#pragma unroll
  for (int o = 0; o < NOUT; ++o) acc[o] = b[o];

  for (int j = 0; j < 32; ++j) {
    const float4 vs = hs[j];
    const float4 vd = hd[j];
#pragma unroll
    for (int o = 0; o < NOUT; ++o) {
      const float4 wu = W4[o * 64 + j];
      const float4 wv = W4[o * 64 + 32 + j];
      acc[o] = fmaf(vs.x, wu.x, fmaf(vs.y, wu.y, fmaf(vs.z, wu.z, fmaf(vs.w, wu.w, acc[o]))));
      acc[o] = fmaf(vd.x, wv.x, fmaf(vd.y, wv.y, fmaf(vd.z, wv.z, fmaf(vd.w, wv.w, acc[o]))));
    }
  }

  float4 r0, r1;
  r0.x = acc[0]; r0.y = acc[1]; r0.z = acc[2]; r0.w = acc[3];
  r1.x = acc[4]; r1.y = acc[5]; r1.z = acc[6]; r1.w = acc[7];
  float4* __restrict__ op = reinterpret_cast<float4*>(out + (size_t)e * NOUT);
  op[0] = r0;
  op[1] = r1;
}

extern "C" void kernel_launch(void* const* d_in, const int* in_sizes, int n_in,
                              void* d_out, int out_size, void* d_ws, size_t ws_size,
                              hipStream_t stream) {
  const float* h   = (const float*)d_in[0];
  const int*   src = (const int*)d_in[1];
  const int*   dst = (const int*)d_in[2];
  const float* W   = (const float*)d_in[3];
  const float* b   = (const float*)d_in[4];
  float* out = (float*)d_out;

  const int n_nodes = in_sizes[0] / NDIM;
  const int n_edges = in_sizes[1];

  const size_t need = (size_t)n_nodes * 16 * sizeof(_Float16);  // 3.2 MB
  if (ws_size >= need) {
    _Float16* P = (_Float16*)d_ws;
    node_proj_kernel<<<(n_nodes + 63) / 64, 256, 0, stream>>>(h, W, b, P, n_nodes);
    edge_score_kernel<<<(n_edges + 1023) / 1024, 256, 0, stream>>>(src, dst, P, out, n_edges);
  } else {
    edge_direct_kernel<<<(n_edges + 255) / 256, 256, 0, stream>>>(h, src, dst, W, b, out, n_edges);
  }
}

// Round 10
// 46.707 us; speedup vs baseline: 1.0492x; 1.0492x over previous
//
#include <hip/hip_runtime.h>

#define NDIM 128   // feature dim D
#define NOUT 8     // output dim

typedef float     f32x4 __attribute__((ext_vector_type(4)));
typedef _Float16  f16x8 __attribute__((ext_vector_type(8)));

// Kernel 1 (v5): per-node projection via MFMA, 2 tiles (32 nodes) per wave.
// D = A(16x128) x B(128x16) per tile as 4 x mfma_f32_16x16x32_f16. No LDS.
// All A/B loads are UNCONDITIONAL (node index clamped; stores guarded) so
// the compiler can batch the 16 dwordx4 A-loads ahead of the MFMAs.
//   P[n][0..7]  = h[n].Wu[o]          (src half)
//   P[n][8..15] = h[n].Wv[o] + b[o]   (dst half, bias baked in)
// Layouts (gfx950 16x16x32): A: row=lane&15, k=(lane>>4)*8+j (8 contiguous);
// B: col=lane&15, same k slice; D: col=lane&15, row=(lane>>4)*4+reg.
__global__ __launch_bounds__(256) void node_proj_kernel(
    const float* __restrict__ h, const float* __restrict__ W,
    const float* __restrict__ b, _Float16* __restrict__ P, int n_nodes) {
  const int lane = threadIdx.x & 63;
  const int wv   = threadIdx.x >> 6;            // wave id in block (0..3)
  const int nb   = blockIdx.x * 128 + wv * 32;  // this wave's base node (2 tiles)
  const int c    = lane & 15;                   // A-row / B-col / D-col
  const int kg   = lane >> 4;                   // k-group (0..3)

  // B fragments: W'[col=c][k]; combined row c: c<8 -> Wu[c], c>=8 -> Wv[c-8].
  // W is [8][256] with Wu = cols 0..127, Wv = cols 128..255.
  const float* __restrict__ wp =
      W + (c & 7) * (2 * NDIM) + (c >> 3) * NDIM + kg * 8;
  f16x8 bf[4];
#pragma unroll
  for (int s = 0; s < 4; ++s) {
    const f32x4 w0 = *reinterpret_cast<const f32x4*>(wp + s * 32);
    const f32x4 w1 = *reinterpret_cast<const f32x4*>(wp + s * 32 + 4);
    f16x8 t;
    t[0] = (_Float16)w0.x; t[1] = (_Float16)w0.y;
    t[2] = (_Float16)w0.z; t[3] = (_Float16)w0.w;
    t[4] = (_Float16)w1.x; t[5] = (_Float16)w1.y;
    t[6] = (_Float16)w1.z; t[7] = (_Float16)w1.w;
    bf[s] = t;
  }

  // A loads for both tiles, clamped (always in-bounds, dup rows harmless).
  const int nmax = n_nodes - 1;
  const int node0 = min(nb + c, nmax);
  const int node1 = min(nb + 16 + c, nmax);
  const float* __restrict__ hp0 = h + (size_t)node0 * NDIM + kg * 8;
  const float* __restrict__ hp1 = h + (size_t)node1 * NDIM + kg * 8;

  f32x4 a0[8], a1[8];
#pragma unroll
  for (int s = 0; s < 4; ++s) {
    a0[s * 2 + 0] = *reinterpret_cast<const f32x4*>(hp0 + s * 32);
    a0[s * 2 + 1] = *reinterpret_cast<const f32x4*>(hp0 + s * 32 + 4);
    a1[s * 2 + 0] = *reinterpret_cast<const f32x4*>(hp1 + s * 32);
    a1[s * 2 + 1] = *reinterpret_cast<const f32x4*>(hp1 + s * 32 + 4);
  }

  f32x4 acc0 = {0.f, 0.f, 0.f, 0.f};
  f32x4 acc1 = {0.f, 0.f, 0.f, 0.f};
#pragma unroll
  for (int s = 0; s < 4; ++s) {
    f16x8 af0, af1;
#pragma unroll
    for (int j = 0; j < 4; ++j) {
      af0[j]     = (_Float16)a0[s * 2 + 0][j];
      af0[j + 4] = (_Float16)a0[s * 2 + 1][j];
      af1[j]     = (_Float16)a1[s * 2 + 0][j];
      af1[j + 4] = (_Float16)a1[s * 2 + 1][j];
    }
    acc0 = __builtin_amdgcn_mfma_f32_16x16x32_f16(af0, bf[s], acc0, 0, 0, 0);
    acc1 = __builtin_amdgcn_mfma_f32_16x16x32_f16(af1, bf[s], acc1, 0, 0, 0);
  }

  // Epilogue: lane writes D rows kg*4..kg*4+3, col c, per tile. Bias on dst half.
  const float bias = (c >= 8) ? b[c - 8] : 0.f;
#pragma unroll
  for (int i = 0; i < 4; ++i) {
    const int r0 = nb + kg * 4 + i;
    if (r0 < n_nodes)
      P[(size_t)r0 * 16 + c] = (_Float16)(acc0[i] + bias);
    const int r1 = nb + 16 + kg * 4 + i;
    if (r1 < n_nodes)
      P[(size_t)r1 * 16 + c] = (_Float16)(acc1[i] + bias);
  }
}

// Kernel 2 (v3, reverted from v4 regression): per-edge gather + add from the
// fp16 P table (3.2MB, fits per-XCD L2). 2 x 16B gathers per edge. Streaming
// traffic (indices in, scores out) is nontemporal to protect P residency.
__global__ __launch_bounds__(256) void edge_score_kernel(
    const int* __restrict__ src, const int* __restrict__ dst,
    const _Float16* __restrict__ P, float* __restrict__ out, int n_edges) {
  const int t = threadIdx.x;
  const int e0 = blockIdx.x * 512 + t;
  const int e1 = e0 + 256;
  const bool v0 = e0 < n_edges;
  const bool v1 = e1 < n_edges;

  const f16x8* __restrict__ Pp = reinterpret_cast<const f16x8*>(P);
  f32x4* __restrict__ op = reinterpret_cast<f32x4*>(out);

  int s0 = 0, d0 = 0, s1 = 0, d1 = 0;
  if (v0) {
    s0 = __builtin_nontemporal_load(src + e0);
    d0 = __builtin_nontemporal_load(dst + e0);
  }
  if (v1) {
    s1 = __builtin_nontemporal_load(src + e1);
    d1 = __builtin_nontemporal_load(dst + e1);
  }

  if (v0) {
    const f16x8 sv = Pp[(size_t)s0 * 2 + 0];   // src half of node s0
    const f16x8 dv = Pp[(size_t)d0 * 2 + 1];   // dst half of node d0
    f32x4 r0, r1;
    r0.x = (float)sv[0] + (float)dv[0]; r0.y = (float)sv[1] + (float)dv[1];
    r0.z = (float)sv[2] + (float)dv[2]; r0.w = (float)sv[3] + (float)dv[3];
    r1.x = (float)sv[4] + (float)dv[4]; r1.y = (float)sv[5] + (float)dv[5];
    r1.z = (float)sv[6] + (float)dv[6]; r1.w = (float)sv[7] + (float)dv[7];
    __builtin_nontemporal_store(r0, op + (size_t)e0 * 2 + 0);
    __builtin_nontemporal_store(r1, op + (size_t)e0 * 2 + 1);
  }
  if (v1) {
    const f16x8 sv = Pp[(size_t)s1 * 2 + 0];
    const f16x8 dv = Pp[(size_t)d1 * 2 + 1];
    f32x4 r0, r1;
    r0.x = (float)sv[0] + (float)dv[0]; r0.y = (float)sv[1] + (float)dv[1];
    r0.z = (float)sv[2] + (float)dv[2]; r0.w = (float)sv[3] + (float)dv[3];
    r1.x = (float)sv[4] + (float)dv[4]; r1.y = (float)sv[5] + (float)dv[5];
    r1.z = (float)sv[6] + (float)dv[6]; r1.w = (float)sv[7] + (float)dv[7];
    __builtin_nontemporal_store(r0, op + (size_t)e1 * 2 + 0);
    __builtin_nontemporal_store(r1, op + (size_t)e1 * 2 + 1);
  }
}

// Fallback (only if workspace is too small): direct per-edge computation.
__global__ __launch_bounds__(256) void edge_direct_kernel(
    const float* __restrict__ h, const int* __restrict__ src,
    const int* __restrict__ dst, const float* __restrict__ W,
    const float* __restrict__ b, float* __restrict__ out, int n_edges) {
  const int e = blockIdx.x * 256 + threadIdx.x;
  if (e >= n_edges) return;
  const int s = src[e];
  const int d = dst[e];
  const float4* __restrict__ hs = reinterpret_cast<const float4*>(h + (size_t)s * NDIM);
  const float4* __restrict__ hd = reinterpret_cast<const float4*>(h + (size_t)d * NDIM);
  const float4* __restrict__ W4 = reinterpret_cast<const float4*>(W);

  float acc[NOUT];
#pragma unroll
  for (int o = 0; o < NOUT; ++o) acc[o] = b[o];

  for (int j = 0; j < 32; ++j) {
    const float4 vs = hs[j];
    const float4 vd = hd[j];
#pragma unroll
    for (int o = 0; o < NOUT; ++o) {
      const float4 wu = W4[o * 64 + j];
      const float4 wv = W4[o * 64 + 32 + j];
      acc[o] = fmaf(vs.x, wu.x, fmaf(vs.y, wu.y, fmaf(vs.z, wu.z, fmaf(vs.w, wu.w, acc[o]))));
      acc[o] = fmaf(vd.x, wv.x, fmaf(vd.y, wv.y, fmaf(vd.z, wv.z, fmaf(vd.w, wv.w, acc[o]))));
    }
  }

  float4 r0, r1;
  r0.x = acc[0]; r0.y = acc[1]; r0.z = acc[2]; r0.w = acc[3];
  r1.x = acc[4]; r1.y = acc[5]; r1.z = acc[6]; r1.w = acc[7];
  float4* __restrict__ op = reinterpret_cast<float4*>(out + (size_t)e * NOUT);
  op[0] = r0;
  op[1] = r1;
}

extern "C" void kernel_launch(void* const* d_in, const int* in_sizes, int n_in,
                              void* d_out, int out_size, void* d_ws, size_t ws_size,
                              hipStream_t stream) {
  const float* h   = (const float*)d_in[0];
  const int*   src = (const int*)d_in[1];
  const int*   dst = (const int*)d_in[2];
  const float* W   = (const float*)d_in[3];
  const float* b   = (const float*)d_in[4];
  float* out = (float*)d_out;

  const int n_nodes = in_sizes[0] / NDIM;
  const int n_edges = in_sizes[1];

  const size_t need = (size_t)n_nodes * 16 * sizeof(_Float16);  // 3.2 MB
  if (ws_size >= need) {
    _Float16* P = (_Float16*)d_ws;
    node_proj_kernel<<<(n_nodes + 127) / 128, 256, 0, stream>>>(h, W, b, P, n_nodes);
    edge_score_kernel<<<(n_edges + 511) / 512, 256, 0, stream>>>(src, dst, P, out, n_edges);
  } else {
    edge_direct_kernel<<<(n_edges + 255) / 256, 256, 0, stream>>>(h, src, dst, W, b, out, n_edges);
  }
}

// Round 11
// 43.067 us; speedup vs baseline: 1.1379x; 1.0845x over previous
//
#include <hip/hip_runtime.h>

#define NDIM 128   // feature dim D
#define NOUT 8     // output dim

typedef float     f32x4 __attribute__((ext_vector_type(4)));
typedef _Float16  f16x8 __attribute__((ext_vector_type(8)));

// Kernel 1 (v6): per-node projection via MFMA, software-pipelined
// grid-stride loop over 16-node tiles. 512 blocks x 4 waves = 2048 waves;
// each wave owns ~3 tiles (stride 2048). Two named register buffers:
// while computing tile t (cvt+MFMA+store), tile t+stride's 16 dwordx4
// loads are already in flight -> load latency hidden under compute.
//   P[n][0..7]  = h[n].Wu[o]          (src half)
//   P[n][8..15] = h[n].Wv[o] + b[o]   (dst half, bias baked in)
// Layouts (gfx950 16x16x32): A: row=lane&15, k=(lane>>4)*8+j; D: col=lane&15,
// row=(lane>>4)*4+reg. All loads unconditional (clamped); stores guarded.
__global__ __launch_bounds__(256) void node_proj_kernel(
    const float* __restrict__ h, const float* __restrict__ W,
    const float* __restrict__ b, _Float16* __restrict__ P, int n_nodes) {
  const int lane = threadIdx.x & 63;
  const int wv   = threadIdx.x >> 6;       // wave id in block (0..3)
  const int c    = lane & 15;              // A-row / B-col / D-col
  const int kg   = lane >> 4;              // k-group (0..3)

  // B fragments: W'[col=c][k]; combined row c: c<8 -> Wu[c], c>=8 -> Wv[c-8].
  const float* __restrict__ wp =
      W + (c & 7) * (2 * NDIM) + (c >> 3) * NDIM + kg * 8;
  f16x8 bf[4];
#pragma unroll
  for (int s = 0; s < 4; ++s) {
    const f32x4 w0 = *reinterpret_cast<const f32x4*>(wp + s * 32);
    const f32x4 w1 = *reinterpret_cast<const f32x4*>(wp + s * 32 + 4);
    f16x8 t;
    t[0] = (_Float16)w0.x; t[1] = (_Float16)w0.y;
    t[2] = (_Float16)w0.z; t[3] = (_Float16)w0.w;
    t[4] = (_Float16)w1.x; t[5] = (_Float16)w1.y;
    t[6] = (_Float16)w1.z; t[7] = (_Float16)w1.w;
    bf[s] = t;
  }

  const int ntile   = (n_nodes + 15) >> 4;
  const int wstride = gridDim.x * 4;           // total waves
  const int nmax    = n_nodes - 1;
  const float bias  = (c >= 8) ? b[c - 8] : 0.f;

  auto load_tile = [&](int tile, f32x4 (&a)[8]) {
    const int node = min(tile * 16 + c, nmax);
    const float* __restrict__ hp = h + (size_t)node * NDIM + kg * 8;
#pragma unroll
    for (int s = 0; s < 4; ++s) {
      a[s * 2 + 0] = *reinterpret_cast<const f32x4*>(hp + s * 32);
      a[s * 2 + 1] = *reinterpret_cast<const f32x4*>(hp + s * 32 + 4);
    }
  };
  auto compute_store = [&](int tile, const f32x4 (&a)[8]) {
    f32x4 acc = {0.f, 0.f, 0.f, 0.f};
#pragma unroll
    for (int s = 0; s < 4; ++s) {
      f16x8 af;
#pragma unroll
      for (int j = 0; j < 4; ++j) {
        af[j]     = (_Float16)a[s * 2 + 0][j];
        af[j + 4] = (_Float16)a[s * 2 + 1][j];
      }
      acc = __builtin_amdgcn_mfma_f32_16x16x32_f16(af, bf[s], acc, 0, 0, 0);
    }
    const int rbase = tile * 16 + kg * 4;
#pragma unroll
    for (int i = 0; i < 4; ++i) {
      const int nrow = rbase + i;
      if (nrow < n_nodes)
        P[(size_t)nrow * 16 + c] = (_Float16)(acc[i] + bias);
    }
  };

  int tile = blockIdx.x * 4 + wv;
  if (tile >= ntile) return;

  f32x4 bufA[8], bufB[8];
  load_tile(tile, bufA);
  while (true) {
    const int t1 = tile + wstride;
    if (t1 >= ntile) { compute_store(tile, bufA); break; }
    load_tile(t1, bufB);               // in flight under A's compute
    compute_store(tile, bufA);
    tile = t1;
    const int t2 = tile + wstride;
    if (t2 >= ntile) { compute_store(tile, bufB); break; }
    load_tile(t2, bufA);               // in flight under B's compute
    compute_store(tile, bufB);
    tile = t2;
  }
}

// Kernel 2 (v3, unchanged): per-edge gather + add from the fp16 P table
// (3.2MB, fits per-XCD L2). 2 x 16B gathers per edge. Streaming traffic
// (indices in, scores out) is nontemporal to protect P residency.
__global__ __launch_bounds__(256) void edge_score_kernel(
    const int* __restrict__ src, const int* __restrict__ dst,
    const _Float16* __restrict__ P, float* __restrict__ out, int n_edges) {
  const int t = threadIdx.x;
  const int e0 = blockIdx.x * 512 + t;
  const int e1 = e0 + 256;
  const bool v0 = e0 < n_edges;
  const bool v1 = e1 < n_edges;

  const f16x8* __restrict__ Pp = reinterpret_cast<const f16x8*>(P);
  f32x4* __restrict__ op = reinterpret_cast<f32x4*>(out);

  int s0 = 0, d0 = 0, s1 = 0, d1 = 0;
  if (v0) {
    s0 = __builtin_nontemporal_load(src + e0);
    d0 = __builtin_nontemporal_load(dst + e0);
  }
  if (v1) {
    s1 = __builtin_nontemporal_load(src + e1);
    d1 = __builtin_nontemporal_load(dst + e1);
  }

  if (v0) {
    const f16x8 sv = Pp[(size_t)s0 * 2 + 0];   // src half of node s0
    const f16x8 dv = Pp[(size_t)d0 * 2 + 1];   // dst half of node d0
    f32x4 r0, r1;
    r0.x = (float)sv[0] + (float)dv[0]; r0.y = (float)sv[1] + (float)dv[1];
    r0.z = (float)sv[2] + (float)dv[2]; r0.w = (float)sv[3] + (float)dv[3];
    r1.x = (float)sv[4] + (float)dv[4]; r1.y = (float)sv[5] + (float)dv[5];
    r1.z = (float)sv[6] + (float)dv[6]; r1.w = (float)sv[7] + (float)dv[7];
    __builtin_nontemporal_store(r0, op + (size_t)e0 * 2 + 0);
    __builtin_nontemporal_store(r1, op + (size_t)e0 * 2 + 1);
  }
  if (v1) {
    const f16x8 sv = Pp[(size_t)s1 * 2 + 0];
    const f16x8 dv = Pp[(size_t)d1 * 2 + 1];
    f32x4 r0, r1;
    r0.x = (float)sv[0] + (float)dv[0]; r0.y = (float)sv[1] + (float)dv[1];
    r0.z = (float)sv[2] + (float)dv[2]; r0.w = (float)sv[3] + (float)dv[3];
    r1.x = (float)sv[4] + (float)dv[4]; r1.y = (float)sv[5] + (float)dv[5];
    r1.z = (float)sv[6] + (float)dv[6]; r1.w = (float)sv[7] + (float)dv[7];
    __builtin_nontemporal_store(r0, op + (size_t)e1 * 2 + 0);
    __builtin_nontemporal_store(r1, op + (size_t)e1 * 2 + 1);
  }
}

// Fallback (only if workspace is too small): direct per-edge computation.
__global__ __launch_bounds__(256) void edge_direct_kernel(
    const float* __restrict__ h, const int* __restrict__ src,
    const int* __restrict__ dst, const float* __restrict__ W,
    const float* __restrict__ b, float* __restrict__ out, int n_edges) {
  const int e = blockIdx.x * 256 + threadIdx.x;
  if (e >= n_edges) return;
  const int s = src[e];
  const int d = dst[e];
  const float4* __restrict__ hs = reinterpret_cast<const float4*>(h + (size_t)s * NDIM);
  const float4* __restrict__ hd = reinterpret_cast<const float4*>(h + (size_t)d * NDIM);
  const float4* __restrict__ W4 = reinterpret_cast<const float4*>(W);

  float acc[NOUT];
#pragma unroll
  for (int o = 0; o < NOUT; ++o) acc[o] = b[o];

  for (int j = 0; j < 32; ++j) {
    const float4 vs = hs[j];
    const float4 vd = hd[j];
#pragma unroll
    for (int o = 0; o < NOUT; ++o) {
      const float4 wu = W4[o * 64 + j];
      const float4 wv = W4[o * 64 + 32 + j];
      acc[o] = fmaf(vs.x, wu.x, fmaf(vs.y, wu.y, fmaf(vs.z, wu.z, fmaf(vs.w, wu.w, acc[o]))));
      acc[o] = fmaf(vd.x, wv.x, fmaf(vd.y, wv.y, fmaf(vd.z, wv.z, fmaf(vd.w, wv.w, acc[o]))));
    }
  }

  float4 r0, r1;
  r0.x = acc[0]; r0.y = acc[1]; r0.z = acc[2]; r0.w = acc[3];
  r1.x = acc[4]; r1.y = acc[5]; r1.z = acc[6]; r1.w = acc[7];
  float4* __restrict__ op = reinterpret_cast<float4*>(out + (size_t)e * NOUT);
  op[0] = r0;
  op[1] = r1;
}

extern "C" void kernel_launch(void* const* d_in, const int* in_sizes, int n_in,
                              void* d_out, int out_size, void* d_ws, size_t ws_size,
                              hipStream_t stream) {
  const float* h   = (const float*)d_in[0];
  const int*   src = (const int*)d_in[1];
  const int*   dst = (const int*)d_in[2];
  const float* W   = (const float*)d_in[3];
  const float* b   = (const float*)d_in[4];
  float* out = (float*)d_out;

  const int n_nodes = in_sizes[0] / NDIM;
  const int n_edges = in_sizes[1];

  const size_t need = (size_t)n_nodes * 16 * sizeof(_Float16);  // 3.2 MB
  if (ws_size >= need) {
    _Float16* P = (_Float16*)d_ws;
    node_proj_kernel<<<512, 256, 0, stream>>>(h, W, b, P, n_nodes);
    edge_score_kernel<<<(n_edges + 511) / 512, 256, 0, stream>>>(src, dst, P, out, n_edges);
  } else {
    edge_direct_kernel<<<(n_edges + 255) / 256, 256, 0, stream>>>(h, src, dst, W, b, out, n_edges);
  }
}